// Round 24
// baseline (131.522 us; speedup 1.0000x reference)
//
#include <hip/hip_runtime.h>
#include <hip/hip_bf16.h>

// B=16, H=64, W=64, C=192, heads=8, key_dim=32, ks=3
// pixels = 65536; model dim = 256.
// QKV row (stride 864 bf16): [ q(256) | kv-interleaved(512): g -> k[4g..],v[4g..] | qb 8x12 (9 used) ]
// Zero row at pixel 65536 handles OOB neighbors.

typedef __bf16 bf16x8_t __attribute__((ext_vector_type(8)));
typedef float f32x4_t __attribute__((ext_vector_type(4)));

#define SCALE 0.17677669529663687f
#define QSTRIDE 864
#define ZROW 65536

static __device__ __forceinline__ unsigned short bfbits(float f) {
    return __builtin_bit_cast(unsigned short, __float2bfloat16(f));
}
static __device__ __forceinline__ float bf2f(unsigned short u) {
    return __bfloat162float(__builtin_bit_cast(__hip_bfloat16, u));
}
static __device__ __forceinline__ float lo16f(unsigned int u) {
    return __builtin_bit_cast(float, u << 16);
}
static __device__ __forceinline__ float hi16f(unsigned int u) {
    return __builtin_bit_cast(float, u & 0xffff0000u);
}

static __device__ __forceinline__ void gload_lds16(const void* g, void* l) {
    __builtin_amdgcn_global_load_lds((const __attribute__((address_space(1))) void*)g,
                                     (__attribute__((address_space(3))) void*)l, 16, 0, 0);
}

// ---------------------------------------------------------------- convert x -> bf16
__global__ void k_convert_x(const float* __restrict__ x, ushort4* __restrict__ xb, int n4) {
    int i = blockIdx.x * blockDim.x + threadIdx.x;
    const int stride = gridDim.x * blockDim.x;
    const float4* x4 = reinterpret_cast<const float4*>(x);
    for (; i < n4; i += stride) {
        float4 v = x4[i];
        ushort4 o;
        o.x = bfbits(v.x); o.y = bfbits(v.y); o.z = bfbits(v.z); o.w = bfbits(v.w);
        xb[i] = o;
    }
}

// ---------------------------------------------------------------- pack weights
__global__ void k_pack(const float* __restrict__ Wq, const float* __restrict__ Wk,
                       const float* __restrict__ Wv, const float* __restrict__ Wo,
                       const float* __restrict__ bq, const float* __restrict__ bk,
                       const float* __restrict__ bv,
                       __hip_bfloat16* __restrict__ WqkvT, __hip_bfloat16* __restrict__ WoT,
                       float* __restrict__ qkvBias, float* __restrict__ wvTab,
                       __hip_bfloat16* __restrict__ QKV) {
    const int idx = blockIdx.x * blockDim.x + threadIdx.x;
    const int T0 = 896 * 192;            // WqkvT
    const int T1 = T0 + 192 * 256;       // WoT
    const int T2 = T1 + 896;             // qkvBias
    const int T3 = T2 + 768;             // wvTab
    const int T4 = T3 + QSTRIDE;         // zero row
    if (idx < T0) {
        const int m = idx / 192, k = idx % 192;
        float v = 0.f;
        if (m < 256) {
            v = Wq[k * 256 + m] * SCALE;
        } else if (m < 768) {
            const int j = m - 256, g = j >> 3, r = j & 7;
            const int d = 4 * g + (r & 3);
            v = (r < 4) ? Wk[k * 256 + d] : Wv[k * 256 + d];
        } else if (m < 864) {
            const int j = m - 768, h = j / 12, n = j % 12;
            if (n < 9) {
                const float dj = (float)(n % 3 - 1), di = (float)(n / 3 - 1);
                float acc = 0.f;
                for (int d = 0; d < 32; ++d) {
                    const int c = h * 32 + d;
                    const float bkv = dj * Wk[192 * 256 + c] + di * Wk[193 * 256 + c] + bk[c];
                    acc += Wq[k * 256 + c] * bkv;
                }
                v = acc * SCALE;
            }
        }
        WqkvT[m * 192 + k] = __float2bfloat16(v);
    } else if (idx < T1) {
        const int j = idx - T0;
        const int c = j >> 8, hd = j & 255;
        WoT[j] = __float2bfloat16(Wo[hd * 192 + c]);
    } else if (idx < T2) {
        const int col = idx - T1;
        float v = 0.f;
        if (col < 256) v = bq[col] * SCALE;
        else if (col >= 768 && col < 864) {
            const int j = col - 768, h = j / 12, n = j % 12;
            if (n < 9) {
                const float dj = (float)(n % 3 - 1), di = (float)(n / 3 - 1);
                float acc = 0.f;
                for (int d = 0; d < 32; ++d) {
                    const int c = h * 32 + d;
                    const float bkv = dj * Wk[192 * 256 + c] + di * Wk[193 * 256 + c] + bk[c];
                    acc += bq[c] * bkv;
                }
                v = acc * SCALE;
            }
        }
        qkvBias[col] = v;
    } else if (idx < T3) {
        const int j = idx - T2;
        const int t = j >> 8, m = j & 255;
        float v;
        if (t == 0)      v = Wv[192 * 256 + m];
        else if (t == 1) v = Wv[193 * 256 + m];
        else             v = bv[m];
        wvTab[j] = v;
    } else if (idx < T4) {
        const int j = idx - T3;
        QKV[(size_t)ZROW * QSTRIDE + j] = __float2bfloat16(0.f);
    }
}

// ---------------------------------------------------------------- LDS-staged MFMA GEMM
// FROZEN r17 config (measured optimum 46.0us across 7 structural variants):
// single 32KB buffer, gload_lds A+B, XOR swizzle (conflict-0), 2 barriers/K-step,
// 8 waves/block, scalar-store epilogue (4 lines per store instruction).
template<int BM, int BN, int WRN, int WCN, int KDIM, int NOUT, int NBX, bool OUTF32, bool BIAS>
__global__ __launch_bounds__(64 * WRN * WCN) void k_gemm_lds(const __hip_bfloat16* __restrict__ A,
                          const __hip_bfloat16* __restrict__ BT,
                          void* __restrict__ Cout,
                          const float* __restrict__ bias, int ldc) {
    constexpr int NW = WRN * WCN;                   // waves per block
    constexpr int WTR = BM / WRN;
    constexpr int WTC = BN / WCN;
    constexpr int FR = WTR / 16;
    constexpr int FC = WTC / 16;
    constexpr int NK = KDIM / 64;
    __shared__ __hip_bfloat16 sA[BM * 64];
    __shared__ __hip_bfloat16 sB[BN * 64];
    const int bid = blockIdx.x;
    const int s = (bid & 7) * ((int)gridDim.x >> 3) + (bid >> 3);
    const int by = s / NBX, bx = s - by * NBX;
    const int tid = threadIdx.x;
    const int wave = tid >> 6, lane = tid & 63;
    const int wr = wave / WCN, wc = wave % WCN;
    const long rowBase = (long)by * BM;
    const long colBase = (long)bx * BN;
    const int lr = lane & 15, lk = lane >> 4;
    const int rx = lr & 7;                          // row&7 of this lane's fragment rows
    const int srow = lane >> 3;                     // 0..7 within 8-row stage chunk
    const int scolsw = ((lane & 7) ^ srow) * 8;     // inverse-swizzled source elem offset

    f32x4_t acc[FR][FC] = {};
    for (int t = 0; t < NK; ++t) {
        const int k0 = t * 64;
        #pragma unroll
        for (int r = 0; r < BM / (8 * NW); ++r) {
            const int row0 = r * (8 * NW) + wave * 8;
            gload_lds16(A + (rowBase + row0 + srow) * KDIM + k0 + scolsw, sA + row0 * 64);
        }
        #pragma unroll
        for (int r = 0; r < BN / (8 * NW) + ((BN % (8 * NW)) ? 1 : 0); ++r) {
            const int row0 = r * (8 * NW) + wave * 8;
            if (row0 < BN)
                gload_lds16(BT + (colBase + row0 + srow) * KDIM + k0 + scolsw, sB + row0 * 64);
        }
        __syncthreads();
        #pragma unroll
        for (int kk = 0; kk < 2; ++kk) {
            const int pc = ((lk + kk * 4) ^ rx) * 8;   // swizzled phys chunk offset
            bf16x8_t a[FR], b[FC];
            #pragma unroll
            for (int fr = 0; fr < FR; ++fr)
                a[fr] = *reinterpret_cast<const bf16x8_t*>(sA + (wr * WTR + fr * 16 + lr) * 64 + pc);
            #pragma unroll
            for (int fc = 0; fc < FC; ++fc)
                b[fc] = *reinterpret_cast<const bf16x8_t*>(sB + (wc * WTC + fc * 16 + lr) * 64 + pc);
            #pragma unroll
            for (int fr = 0; fr < FR; ++fr) {
                #pragma unroll
                for (int fc = 0; fc < FC; ++fc)
                    acc[fr][fc] = __builtin_amdgcn_mfma_f32_16x16x32_bf16(a[fr], b[fc], acc[fr][fc], 0, 0, 0);
            }
        }
        __syncthreads();
    }
    const int rowSub = (lane >> 4) * 4;
    const int colSub = lane & 15;
    #pragma unroll
    for (int fr = 0; fr < FR; ++fr) {
        #pragma unroll
        for (int fc = 0; fc < FC; ++fc) {
            const long col = colBase + wc * WTC + fc * 16 + colSub;
            if (col >= NOUT) continue;
            float bvv = BIAS ? bias[col] : 0.f;
            #pragma unroll
            for (int r = 0; r < 4; ++r) {
                const long row = rowBase + wr * WTR + fr * 16 + rowSub + r;
                float v = acc[fr][fc][r] + bvv;
                if constexpr (OUTF32) ((float*)Cout)[row * ldc + col] = v;
                else ((__hip_bfloat16*)Cout)[row * ldc + col] = __float2bfloat16(v);
            }
        }
    }
}

// ---------------------------------------------------------------- fused attention + out-proj
// Phase 1 (per wave, 2x2 quad): r17's gather/softmax/PV -> o-vector per pixel,
// written bf16 to LDS oS[16][264] (264-stride -> 2-way bank aliasing, free).
// Phase 2 (block GEMM): [16,256] x WoT[192,256]^T -> d_out f32 + bo directly.
// Each wave: 3 col-tiles x 8 K-steps = 24 MFMA; B-frags from L2-hot WoT (98KB).
// Removes the O buffer round-trip (66MB) and the separate out-proj kernel.
__global__ __launch_bounds__(256) void k_attn_out(const __hip_bfloat16* __restrict__ QKV,
                       const float* __restrict__ wvTab,
                       const __hip_bfloat16* __restrict__ WoT,
                       const float* __restrict__ bo,
                       float* __restrict__ out) {
    __shared__ __hip_bfloat16 oS[16][264];
    const int wave = threadIdx.x >> 6;
    const int lane = threadIdx.x & 63;
    const int bid = blockIdx.x;
    const int sblk = (bid & 7) * 512 + (bid >> 3);    // XCD-chunked swizzle (4096 wgs)
    const int qd = sblk * 4 + wave;                   // quad id [0,16384)
    const int b = qd >> 10;
    const int qy = (qd >> 5) & 31, qx = qd & 31;
    const int y = qy << 1, x = qx << 1;
    const int p00 = (b << 12) | (y << 6) | x;
    const int h = lane >> 3, dg = lane & 7;
    const int idx = h * 32 + dg * 4;
    const char* baseQ = reinterpret_cast<const char*>(QKV);
    const int laneOff = 512 + 128 * h + 16 * dg;

    // 16 branch-free gathers over the 4x4 union window (OOB -> zero row)
    uint4 kv[16];
    #pragma unroll
    for (int m = 0; m < 16; ++m) {
        const int rr = m >> 2, cc = m & 3;
        const int ny = y + rr - 1, nx = x + cc - 1;
        const bool inb = ((unsigned)ny < 64u) & ((unsigned)nx < 64u);
        const long row = inb ? (long)((b << 12) | (ny << 6) | nx) : (long)ZROW;
        kv[m] = *reinterpret_cast<const uint4*>(baseQ + row * (QSTRIDE * 2) + laneOff);
    }

    const float4 w0 = *reinterpret_cast<const float4*>(wvTab + idx);
    const float4 w1 = *reinterpret_cast<const float4*>(wvTab + 256 + idx);
    const float4 w2 = *reinterpret_cast<const float4*>(wvTab + 512 + idx);

    #pragma unroll
    for (int pxi = 0; pxi < 4; ++pxi) {
        const int dy = pxi >> 1, dx = pxi & 1;
        const int p = p00 + dy * 64 + dx;
        const __hip_bfloat16* rowQ = QKV + (size_t)p * QSTRIDE;
        const ushort4 qu = *reinterpret_cast<const ushort4*>(rowQ + idx);
        const ushort4 qa = *reinterpret_cast<const ushort4*>(rowQ + 768 + 12 * h);
        const ushort4 qbv = *reinterpret_cast<const ushort4*>(rowQ + 772 + 12 * h);
        const unsigned short qc = *reinterpret_cast<const unsigned short*>(rowQ + 776 + 12 * h);
        const float q0 = bf2f(qu.x), q1 = bf2f(qu.y), q2 = bf2f(qu.z), q3 = bf2f(qu.w);
        const float qb[9] = { bf2f(qa.x), bf2f(qa.y), bf2f(qa.z), bf2f(qa.w),
                              bf2f(qbv.x), bf2f(qbv.y), bf2f(qbv.z), bf2f(qbv.w), bf2f(qc) };

        float sc[9];
        #pragma unroll
        for (int n = 0; n < 9; ++n) {
            const int m = (dy + n / 3) * 4 + dx + n % 3;
            const uint4 k = kv[m];
            float s = fmaf(q0, lo16f(k.x), fmaf(q1, hi16f(k.x),
                      fmaf(q2, lo16f(k.y), q3 * hi16f(k.y))));
            s += __shfl_xor(s, 1);
            s += __shfl_xor(s, 2);
            s += __shfl_xor(s, 4);
            sc[n] = s + qb[n];
        }
        float mx = sc[0];
        #pragma unroll
        for (int n = 1; n < 9; ++n) mx = fmaxf(mx, sc[n]);
        float sum = 0.f;
        #pragma unroll
        for (int n = 0; n < 9; ++n) { sc[n] = __expf(sc[n] - mx); sum += sc[n]; }
        const float inv = 1.0f / sum;
        const float Ej = (sc[2] + sc[5] + sc[8]) - (sc[0] + sc[3] + sc[6]);
        const float Ei = (sc[6] + sc[7] + sc[8]) - (sc[0] + sc[1] + sc[2]);

        float o0 = 0.f, o1 = 0.f, o2 = 0.f, o3 = 0.f;
        #pragma unroll
        for (int n = 0; n < 9; ++n) {
            const int m = (dy + n / 3) * 4 + dx + n % 3;
            const uint4 k = kv[m];
            o0 = fmaf(sc[n], lo16f(k.z), o0);
            o1 = fmaf(sc[n], hi16f(k.z), o1);
            o2 = fmaf(sc[n], lo16f(k.w), o2);
            o3 = fmaf(sc[n], hi16f(k.w), o3);
        }
        ushort4 ov;
        ov.x = bfbits(fmaf(Ej, w0.x, fmaf(Ei, w1.x, o0)) * inv + w2.x);
        ov.y = bfbits(fmaf(Ej, w0.y, fmaf(Ei, w1.y, o1)) * inv + w2.y);
        ov.z = bfbits(fmaf(Ej, w0.z, fmaf(Ei, w1.z, o2)) * inv + w2.z);
        ov.w = bfbits(fmaf(Ej, w0.w, fmaf(Ei, w1.w, o3)) * inv + w2.w);
        *reinterpret_cast<ushort4*>(&oS[wave * 4 + pxi][idx]) = ov;
    }
    __syncthreads();

    // ---- phase 2: [16,256] x WoT^T -> out[16 pixels][192] + bo
    const int lr = lane & 15, lk = lane >> 4;
    f32x4_t acc[3] = {};
    #pragma unroll
    for (int k = 0; k < 8; ++k) {
        const bf16x8_t a = *reinterpret_cast<const bf16x8_t*>(&oS[lr][k * 32 + lk * 8]);
        #pragma unroll
        for (int t = 0; t < 3; ++t) {
            const int col = (wave * 3 + t) * 16 + lr;
            const bf16x8_t bfr = *reinterpret_cast<const bf16x8_t*>(WoT + col * 256 + k * 32 + lk * 8);
            acc[t] = __builtin_amdgcn_mfma_f32_16x16x32_bf16(a, bfr, acc[t], 0, 0, 0);
        }
    }
    // C mapping: col=lane&15 (within tile), row=(lane>>4)*4+r; row g*4+r = wave g's pixel r
    const int g = lane >> 4;
    const int qd2 = sblk * 4 + g;
    const int b2 = qd2 >> 10;
    const int y2 = ((qd2 >> 5) & 31) << 1;
    const int x2 = (qd2 & 31) << 1;
    const int pbase = (b2 << 12) | (y2 << 6) | x2;
    #pragma unroll
    for (int t = 0; t < 3; ++t) {
        const int col = (wave * 3 + t) * 16 + (lane & 15);
        const float bov = bo[col];
        #pragma unroll
        for (int r = 0; r < 4; ++r) {
            const int p = pbase + (r >> 1) * 64 + (r & 1);
            out[(size_t)p * 192 + col] = acc[t][r] + bov;
        }
    }
}

// ---------------------------------------------------------------- launch
extern "C" void kernel_launch(void* const* d_in, const int* in_sizes, int n_in,
                              void* d_out, int out_size, void* d_ws, size_t ws_size,
                              hipStream_t stream) {
    (void)in_sizes; (void)n_in; (void)out_size; (void)ws_size;
    const float* x  = (const float*)d_in[0];
    const float* Wq = (const float*)d_in[1];
    const float* bq = (const float*)d_in[2];
    const float* Wk = (const float*)d_in[3];
    const float* bk = (const float*)d_in[4];
    const float* Wv = (const float*)d_in[5];
    const float* bv = (const float*)d_in[6];
    const float* Wo = (const float*)d_in[7];
    const float* bo = (const float*)d_in[8];

    char* ws = (char*)d_ws;
    // ws layout (no O buffer anymore; total ~147.3 MB):
    __hip_bfloat16* xb    = (__hip_bfloat16*)(ws + 0);           // 25,165,824 B
    __hip_bfloat16* QKV   = (__hip_bfloat16*)(ws + 33554432);    // 65537*864*2 = 113,247,936 B
    __hip_bfloat16* WqkvT = (__hip_bfloat16*)(ws + 146802368);   // 896*192*2 = 344,064
    __hip_bfloat16* WoT   = (__hip_bfloat16*)(ws + 147146432);   // 192*256*2 = 98,304
    float* qkvBias        = (float*)(ws + 147244736);            // 896*4 = 3,584
    float* wvTab          = (float*)(ws + 147248320);            // 3*256*4 = 3,072

    k_convert_x<<<4096, 256, 0, stream>>>(x, (ushort4*)xb, 12582912 / 4);
    k_pack<<<874, 256, 0, stream>>>(Wq, Wk, Wv, Wo, bq, bk, bv, WqkvT, WoT, qkvBias, wvTab, QKV);
    // QKV+QB projection: [65536,192] x [192,896(864 used)] -> bf16, stride 864
    // FROZEN r17 config: 128x128 tile, 8-wave 512-thread blocks
    k_gemm_lds<128, 128, 2, 4, 192, 864, 7, false, true>
        <<<3584, 512, 0, stream>>>(xb, WqkvT, (void*)QKV, qkvBias, QSTRIDE);
    // fused attention + out-projection: 2x2 quad per wave, block GEMM to d_out
    k_attn_out<<<4096, 256, 0, stream>>>(QKV, wvTab, WoT, bo, (float*)d_out);
}

// Round 25
// 109.250 us; speedup vs baseline: 1.2039x; 1.2039x over previous
//
#include <hip/hip_runtime.h>
#include <hip/hip_bf16.h>

// B=16, H=64, W=64, C=192, heads=8, key_dim=32, ks=3
// pixels = 65536; model dim = 256.
// QKV row (stride 864 bf16): [ q(256) | kv-interleaved(512): g -> k[4g..],v[4g..] | qb 8x12 (9 used) ]
// Zero row at pixel 65536 handles OOB neighbors.
//
// BEST MEASURED CONFIG (round 17: 110.57us). Reverted here after the fused
// attn+out-proj (r24: 131.5us, 524K bank conflicts + 28% occupancy) regressed.

typedef __bf16 bf16x8_t __attribute__((ext_vector_type(8)));
typedef float f32x4_t __attribute__((ext_vector_type(4)));

#define SCALE 0.17677669529663687f
#define QSTRIDE 864
#define ZROW 65536

static __device__ __forceinline__ unsigned short bfbits(float f) {
    return __builtin_bit_cast(unsigned short, __float2bfloat16(f));
}
static __device__ __forceinline__ float bf2f(unsigned short u) {
    return __bfloat162float(__builtin_bit_cast(__hip_bfloat16, u));
}
static __device__ __forceinline__ float lo16f(unsigned int u) {
    return __builtin_bit_cast(float, u << 16);
}
static __device__ __forceinline__ float hi16f(unsigned int u) {
    return __builtin_bit_cast(float, u & 0xffff0000u);
}

static __device__ __forceinline__ void gload_lds16(const void* g, void* l) {
    __builtin_amdgcn_global_load_lds((const __attribute__((address_space(1))) void*)g,
                                     (__attribute__((address_space(3))) void*)l, 16, 0, 0);
}

// ---------------------------------------------------------------- convert x -> bf16
// Memory-roofline kernel (~12 us). Fusing into the GEMM (r10) cost ~40us of GEMM
// time -- keep standalone.
__global__ void k_convert_x(const float* __restrict__ x, ushort4* __restrict__ xb, int n4) {
    int i = blockIdx.x * blockDim.x + threadIdx.x;
    const int stride = gridDim.x * blockDim.x;
    const float4* x4 = reinterpret_cast<const float4*>(x);
    for (; i < n4; i += stride) {
        float4 v = x4[i];
        ushort4 o;
        o.x = bfbits(v.x); o.y = bfbits(v.y); o.z = bfbits(v.z); o.w = bfbits(v.w);
        xb[i] = o;
    }
}

// ---------------------------------------------------------------- pack weights
__global__ void k_pack(const float* __restrict__ Wq, const float* __restrict__ Wk,
                       const float* __restrict__ Wv, const float* __restrict__ Wo,
                       const float* __restrict__ bq, const float* __restrict__ bk,
                       const float* __restrict__ bv,
                       __hip_bfloat16* __restrict__ WqkvT, __hip_bfloat16* __restrict__ WoT,
                       float* __restrict__ qkvBias, float* __restrict__ wvTab,
                       __hip_bfloat16* __restrict__ QKV) {
    const int idx = blockIdx.x * blockDim.x + threadIdx.x;
    const int T0 = 896 * 192;            // WqkvT
    const int T1 = T0 + 192 * 256;       // WoT
    const int T2 = T1 + 896;             // qkvBias
    const int T3 = T2 + 768;             // wvTab
    const int T4 = T3 + QSTRIDE;         // zero row
    if (idx < T0) {
        const int m = idx / 192, k = idx % 192;
        float v = 0.f;
        if (m < 256) {
            v = Wq[k * 256 + m] * SCALE;
        } else if (m < 768) {
            const int j = m - 256, g = j >> 3, r = j & 7;
            const int d = 4 * g + (r & 3);
            v = (r < 4) ? Wk[k * 256 + d] : Wv[k * 256 + d];
        } else if (m < 864) {
            const int j = m - 768, h = j / 12, n = j % 12;
            if (n < 9) {
                const float dj = (float)(n % 3 - 1), di = (float)(n / 3 - 1);
                float acc = 0.f;
                for (int d = 0; d < 32; ++d) {
                    const int c = h * 32 + d;
                    const float bkv = dj * Wk[192 * 256 + c] + di * Wk[193 * 256 + c] + bk[c];
                    acc += Wq[k * 256 + c] * bkv;
                }
                v = acc * SCALE;
            }
        }
        WqkvT[m * 192 + k] = __float2bfloat16(v);
    } else if (idx < T1) {
        const int j = idx - T0;
        const int c = j >> 8, hd = j & 255;
        WoT[j] = __float2bfloat16(Wo[hd * 192 + c]);
    } else if (idx < T2) {
        const int col = idx - T1;
        float v = 0.f;
        if (col < 256) v = bq[col] * SCALE;
        else if (col >= 768 && col < 864) {
            const int j = col - 768, h = j / 12, n = j % 12;
            if (n < 9) {
                const float dj = (float)(n % 3 - 1), di = (float)(n / 3 - 1);
                float acc = 0.f;
                for (int d = 0; d < 32; ++d) {
                    const int c = h * 32 + d;
                    const float bkv = dj * Wk[192 * 256 + c] + di * Wk[193 * 256 + c] + bk[c];
                    acc += bq[c] * bkv;
                }
                v = acc * SCALE;
            }
        }
        qkvBias[col] = v;
    } else if (idx < T3) {
        const int j = idx - T2;
        const int t = j >> 8, m = j & 255;
        float v;
        if (t == 0)      v = Wv[192 * 256 + m];
        else if (t == 1) v = Wv[193 * 256 + m];
        else             v = bv[m];
        wvTab[j] = v;
    } else if (idx < T4) {
        const int j = idx - T3;
        QKV[(size_t)ZROW * QSTRIDE + j] = __float2bfloat16(0.f);
    }
}

// ---------------------------------------------------------------- LDS-staged MFMA GEMM
// FROZEN r17 config (measured optimum across 8 structural variants): single 32KB
// buffer, gload_lds A+B, XOR swizzle (conflict-0), 2 barriers/K-step, 8 waves/block,
// scalar-store epilogue (4 cache lines per store instruction).
template<int BM, int BN, int WRN, int WCN, int KDIM, int NOUT, int NBX, bool OUTF32, bool BIAS>
__global__ __launch_bounds__(64 * WRN * WCN) void k_gemm_lds(const __hip_bfloat16* __restrict__ A,
                          const __hip_bfloat16* __restrict__ BT,
                          void* __restrict__ Cout,
                          const float* __restrict__ bias, int ldc) {
    constexpr int NW = WRN * WCN;                   // waves per block
    constexpr int WTR = BM / WRN;
    constexpr int WTC = BN / WCN;
    constexpr int FR = WTR / 16;
    constexpr int FC = WTC / 16;
    constexpr int NK = KDIM / 64;
    __shared__ __hip_bfloat16 sA[BM * 64];
    __shared__ __hip_bfloat16 sB[BN * 64];
    const int bid = blockIdx.x;
    const int s = (bid & 7) * ((int)gridDim.x >> 3) + (bid >> 3);
    const int by = s / NBX, bx = s - by * NBX;
    const int tid = threadIdx.x;
    const int wave = tid >> 6, lane = tid & 63;
    const int wr = wave / WCN, wc = wave % WCN;
    const long rowBase = (long)by * BM;
    const long colBase = (long)bx * BN;
    const int lr = lane & 15, lk = lane >> 4;
    const int rx = lr & 7;                          // row&7 of this lane's fragment rows
    const int srow = lane >> 3;                     // 0..7 within 8-row stage chunk
    const int scolsw = ((lane & 7) ^ srow) * 8;     // inverse-swizzled source elem offset

    f32x4_t acc[FR][FC] = {};
    for (int t = 0; t < NK; ++t) {
        const int k0 = t * 64;
        #pragma unroll
        for (int r = 0; r < BM / (8 * NW); ++r) {
            const int row0 = r * (8 * NW) + wave * 8;
            gload_lds16(A + (rowBase + row0 + srow) * KDIM + k0 + scolsw, sA + row0 * 64);
        }
        #pragma unroll
        for (int r = 0; r < BN / (8 * NW) + ((BN % (8 * NW)) ? 1 : 0); ++r) {
            const int row0 = r * (8 * NW) + wave * 8;
            if (row0 < BN)
                gload_lds16(BT + (colBase + row0 + srow) * KDIM + k0 + scolsw, sB + row0 * 64);
        }
        __syncthreads();
        #pragma unroll
        for (int kk = 0; kk < 2; ++kk) {
            const int pc = ((lk + kk * 4) ^ rx) * 8;   // swizzled phys chunk offset
            bf16x8_t a[FR], b[FC];
            #pragma unroll
            for (int fr = 0; fr < FR; ++fr)
                a[fr] = *reinterpret_cast<const bf16x8_t*>(sA + (wr * WTR + fr * 16 + lr) * 64 + pc);
            #pragma unroll
            for (int fc = 0; fc < FC; ++fc)
                b[fc] = *reinterpret_cast<const bf16x8_t*>(sB + (wc * WTC + fc * 16 + lr) * 64 + pc);
            #pragma unroll
            for (int fr = 0; fr < FR; ++fr) {
                #pragma unroll
                for (int fc = 0; fc < FC; ++fc)
                    acc[fr][fc] = __builtin_amdgcn_mfma_f32_16x16x32_bf16(a[fr], b[fc], acc[fr][fc], 0, 0, 0);
            }
        }
        __syncthreads();
    }
    const int rowSub = (lane >> 4) * 4;
    const int colSub = lane & 15;
    #pragma unroll
    for (int fr = 0; fr < FR; ++fr) {
        #pragma unroll
        for (int fc = 0; fc < FC; ++fc) {
            const long col = colBase + wc * WTC + fc * 16 + colSub;
            if (col >= NOUT) continue;
            float bvv = BIAS ? bias[col] : 0.f;
            #pragma unroll
            for (int r = 0; r < 4; ++r) {
                const long row = rowBase + wr * WTR + fr * 16 + rowSub + r;
                float v = acc[fr][fc][r] + bvv;
                if constexpr (OUTF32) ((float*)Cout)[row * ldc + col] = v;
                else ((__hip_bfloat16*)Cout)[row * ldc + col] = __float2bfloat16(v);
            }
        }
    }
}

// ---------------------------------------------------------------- attention gather
// 2x2 PIXEL QUAD per wave: union window = 4x4 = 16 positions -> 4 gathers/pixel.
// Per-pixel compute runs SEQUENTIALLY (reusing sc/o registers); only kv[16] persists.
__global__ __launch_bounds__(256) void k_attn(const __hip_bfloat16* __restrict__ QKV,
                       const float* __restrict__ wvTab,
                       __hip_bfloat16* __restrict__ O) {
    const int wave = threadIdx.x >> 6;
    const int lane = threadIdx.x & 63;
    const int bid = blockIdx.x;
    const int sblk = (bid & 7) * 512 + (bid >> 3);    // XCD-chunked swizzle (4096 wgs)
    const int qd = sblk * 4 + wave;                   // quad id [0,16384)
    const int b = qd >> 10;                           // 1024 quads per image
    const int qy = (qd >> 5) & 31, qx = qd & 31;
    const int y = qy << 1, x = qx << 1;
    const int p00 = (b << 12) | (y << 6) | x;
    const int h = lane >> 3, dg = lane & 7;
    const int idx = h * 32 + dg * 4;
    const char* baseQ = reinterpret_cast<const char*>(QKV);
    const int laneOff = 512 + 128 * h + 16 * dg;      // byte offset of this lane's kv group

    // 16 branch-free gathers over the 4x4 union window (OOB -> zero row)
    uint4 kv[16];
    #pragma unroll
    for (int m = 0; m < 16; ++m) {
        const int rr = m >> 2, cc = m & 3;
        const int ny = y + rr - 1, nx = x + cc - 1;
        const bool inb = ((unsigned)ny < 64u) & ((unsigned)nx < 64u);
        const long row = inb ? (long)((b << 12) | (ny << 6) | nx) : (long)ZROW;
        kv[m] = *reinterpret_cast<const uint4*>(baseQ + row * (QSTRIDE * 2) + laneOff);
    }

    const float4 w0 = *reinterpret_cast<const float4*>(wvTab + idx);
    const float4 w1 = *reinterpret_cast<const float4*>(wvTab + 256 + idx);
    const float4 w2 = *reinterpret_cast<const float4*>(wvTab + 512 + idx);

    #pragma unroll
    for (int pxi = 0; pxi < 4; ++pxi) {
        const int dy = pxi >> 1, dx = pxi & 1;
        const int p = p00 + dy * 64 + dx;
        const __hip_bfloat16* rowQ = QKV + (size_t)p * QSTRIDE;
        const ushort4 qu = *reinterpret_cast<const ushort4*>(rowQ + idx);
        const ushort4 qa = *reinterpret_cast<const ushort4*>(rowQ + 768 + 12 * h);
        const ushort4 qbv = *reinterpret_cast<const ushort4*>(rowQ + 772 + 12 * h);
        const unsigned short qc = *reinterpret_cast<const unsigned short*>(rowQ + 776 + 12 * h);
        const float q0 = bf2f(qu.x), q1 = bf2f(qu.y), q2 = bf2f(qu.z), q3 = bf2f(qu.w);
        const float qb[9] = { bf2f(qa.x), bf2f(qa.y), bf2f(qa.z), bf2f(qa.w),
                              bf2f(qbv.x), bf2f(qbv.y), bf2f(qbv.z), bf2f(qbv.w), bf2f(qc) };

        float sc[9];
        #pragma unroll
        for (int n = 0; n < 9; ++n) {
            const int m = (dy + n / 3) * 4 + dx + n % 3;   // compile-time per (pxi,n)
            const uint4 k = kv[m];
            float s = fmaf(q0, lo16f(k.x), fmaf(q1, hi16f(k.x),
                      fmaf(q2, lo16f(k.y), q3 * hi16f(k.y))));
            s += __shfl_xor(s, 1);
            s += __shfl_xor(s, 2);
            s += __shfl_xor(s, 4);
            sc[n] = s + qb[n];
        }
        float mx = sc[0];
        #pragma unroll
        for (int n = 1; n < 9; ++n) mx = fmaxf(mx, sc[n]);
        float sum = 0.f;
        #pragma unroll
        for (int n = 0; n < 9; ++n) { sc[n] = __expf(sc[n] - mx); sum += sc[n]; }
        const float inv = 1.0f / sum;
        const float Ej = (sc[2] + sc[5] + sc[8]) - (sc[0] + sc[3] + sc[6]);
        const float Ei = (sc[6] + sc[7] + sc[8]) - (sc[0] + sc[1] + sc[2]);

        float o0 = 0.f, o1 = 0.f, o2 = 0.f, o3 = 0.f;
        #pragma unroll
        for (int n = 0; n < 9; ++n) {
            const int m = (dy + n / 3) * 4 + dx + n % 3;
            const uint4 k = kv[m];
            o0 = fmaf(sc[n], lo16f(k.z), o0);
            o1 = fmaf(sc[n], hi16f(k.z), o1);
            o2 = fmaf(sc[n], lo16f(k.w), o2);
            o3 = fmaf(sc[n], hi16f(k.w), o3);
        }
        ushort4 ov;
        ov.x = bfbits(fmaf(Ej, w0.x, fmaf(Ei, w1.x, o0)) * inv + w2.x);
        ov.y = bfbits(fmaf(Ej, w0.y, fmaf(Ei, w1.y, o1)) * inv + w2.y);
        ov.z = bfbits(fmaf(Ej, w0.z, fmaf(Ei, w1.z, o2)) * inv + w2.z);
        ov.w = bfbits(fmaf(Ej, w0.w, fmaf(Ei, w1.w, o3)) * inv + w2.w);
        *reinterpret_cast<ushort4*>(O + (size_t)p * 256 + idx) = ov;
    }
}

// ---------------------------------------------------------------- launch
extern "C" void kernel_launch(void* const* d_in, const int* in_sizes, int n_in,
                              void* d_out, int out_size, void* d_ws, size_t ws_size,
                              hipStream_t stream) {
    (void)in_sizes; (void)n_in; (void)out_size; (void)ws_size;
    const float* x  = (const float*)d_in[0];
    const float* Wq = (const float*)d_in[1];
    const float* bq = (const float*)d_in[2];
    const float* Wk = (const float*)d_in[3];
    const float* bk = (const float*)d_in[4];
    const float* Wv = (const float*)d_in[5];
    const float* bv = (const float*)d_in[6];
    const float* Wo = (const float*)d_in[7];
    const float* bo = (const float*)d_in[8];

    char* ws = (char*)d_ws;
    // ws layout (O overlaps dead xb; total ~147.3 MB):
    __hip_bfloat16* xb    = (__hip_bfloat16*)(ws + 0);           // 25,165,824 B
    __hip_bfloat16* O     = (__hip_bfloat16*)(ws + 0);           // 33,554,432 B (xb dead by then)
    __hip_bfloat16* QKV   = (__hip_bfloat16*)(ws + 33554432);    // 65537*864*2 = 113,247,936 B
    __hip_bfloat16* WqkvT = (__hip_bfloat16*)(ws + 146802368);   // 896*192*2 = 344,064
    __hip_bfloat16* WoT   = (__hip_bfloat16*)(ws + 147146432);   // 192*256*2 = 98,304
    float* qkvBias        = (float*)(ws + 147244736);            // 896*4 = 3,584
    float* wvTab          = (float*)(ws + 147248320);            // 3*256*4 = 3,072

    k_convert_x<<<4096, 256, 0, stream>>>(x, (ushort4*)xb, 12582912 / 4);
    k_pack<<<874, 256, 0, stream>>>(Wq, Wk, Wv, Wo, bq, bk, bv, WqkvT, WoT, qkvBias, wvTab, QKV);
    // QKV+QB projection: [65536,192] x [192,896(864 used)] -> bf16, stride 864
    // 8-wave blocks (WRN=2 x WCN=4, 512 threads)
    k_gemm_lds<128, 128, 2, 4, 192, 864, 7, false, true>
        <<<3584, 512, 0, stream>>>(xb, WqkvT, (void*)QKV, qkvBias, QSTRIDE);
    // attention: 2x2 pixel quad per wave, 4 waves per block
    k_attn<<<4096, 256, 0, stream>>>(QKV, wvTab, O);
    // output projection: [65536,256] x [256,192] -> f32 + bo
    k_gemm_lds<128, 64, 2, 4, 256, 192, 3, true, true>
        <<<1536, 512, 0, stream>>>(O, WoT, d_out, bo, 192);
}